// Round 3
// baseline (54.429 us; speedup 1.0000x reference)
//
#include <hip/hip_runtime.h>

#define HH 160
#define WW 160
#define CC 32
#define NN 8
#define NPAIR 80   // WW/2

typedef float f32x2 __attribute__((ext_vector_type(2)));
typedef float f32x4 __attribute__((ext_vector_type(4)));

// One thread: (n, h, w-pair, 8-channel group). 36 kernel taps loaded once as
// float2 (shared across channels), feature rows loaded as float2+2 scalars,
// outputs stored as nontemporal float4. h is XCD-chunk-swizzled (160 = 8*20)
// so the 3-row feature reuse window stays inside one XCD's L2.
__global__ __launch_bounds__(320) void pixelconv_k(
    const float* __restrict__ feature,   // [8,32,160,160]
    const float* __restrict__ kern,      // [8,36,160,160]
    float* __restrict__ out)             // [8,32,320,320]
{
    const int by = blockIdx.y;                 // 0..159
    const int h  = (by & 7) * 20 + (by >> 3);  // XCD-chunked h swizzle
    const int n  = blockIdx.z;

    const int t  = threadIdx.x;     // 0..319
    const int cg = t / NPAIR;       // 0..3  (channel group)
    const int p  = t % NPAIR;       // 0..79 (w-pair index)
    const int w0 = 2 * p;

    // Hoist 36 per-pixel kernel values for BOTH pixels of the pair.
    // kern[n][j][h][w], j = k*4 + s, k = dx*3 + dy
    f32x2 kv[36];
    const float* kp = kern + (((size_t)n * 36) * HH + h) * WW + w0;
    #pragma unroll
    for (int j = 0; j < 36; ++j)
        kv[j] = *(const f32x2*)(kp + (size_t)j * HH * WW);

    const bool hm = (h > 0), hp = (h < HH - 1);
    const bool wm = (p > 0), wp = (p < NPAIR - 1);

    float* outn = out + (size_t)n * CC * (2 * HH) * (2 * WW);

    #pragma unroll
    for (int i = 0; i < 8; ++i) {
        const int c = cg * 8 + i;
        const float* fc = feature + ((size_t)(n * CC + c) * HH) * WW + w0;

        // rows h-1..h+1, cols w0-1..w0+2  -> r[3][4]
        float r[3][4];
        #pragma unroll
        for (int dy = 0; dy < 3; ++dy) {
            const int hh = h + dy - 1;
            const bool okh = (dy == 1) || (dy == 0 ? hm : hp);
            const float* rowp = fc + hh * WW;
            f32x2 mid = okh ? *(const f32x2*)rowp : (f32x2){0.f, 0.f};
            r[dy][1] = mid.x;
            r[dy][2] = mid.y;
            r[dy][0] = (okh && wm) ? rowp[-1] : 0.f;
            r[dy][3] = (okh && wp) ? rowp[2]  : 0.f;
        }

        float a00 = 0.f, a01 = 0.f, a02 = 0.f, a03 = 0.f;   // pixel w0
        float a10 = 0.f, a11 = 0.f, a12 = 0.f, a13 = 0.f;   // pixel w0+1
        #pragma unroll
        for (int dx = 0; dx < 3; ++dx) {
            #pragma unroll
            for (int dy = 0; dy < 3; ++dy) {
                const int k = dx * 3 + dy;
                const float f0 = r[dy][dx];      // col w0 + dx - 1
                const float f1 = r[dy][dx + 1];  // col w0 + dx
                a00 = fmaf(f0, kv[k * 4 + 0].x, a00);
                a01 = fmaf(f0, kv[k * 4 + 1].x, a01);
                a02 = fmaf(f0, kv[k * 4 + 2].x, a02);
                a03 = fmaf(f0, kv[k * 4 + 3].x, a03);
                a10 = fmaf(f1, kv[k * 4 + 0].y, a10);
                a11 = fmaf(f1, kv[k * 4 + 1].y, a11);
                a12 = fmaf(f1, kv[k * 4 + 2].y, a12);
                a13 = fmaf(f1, kv[k * 4 + 3].y, a13);
            }
        }

        // pixel shuffle: s = r1*2+r2 -> out[2h+r1][2w+r2]; pair -> float4 row
        float* oc = outn + (size_t)c * (2 * HH) * (2 * WW);
        f32x4 v0 = {a00, a01, a10, a11};  // row 2h,   cols 2w0..2w0+3
        f32x4 v1 = {a02, a03, a12, a13};  // row 2h+1, cols 2w0..2w0+3
        __builtin_nontemporal_store(v0, (f32x4*)(oc + (size_t)(2 * h)     * (2 * WW) + 2 * w0));
        __builtin_nontemporal_store(v1, (f32x4*)(oc + (size_t)(2 * h + 1) * (2 * WW) + 2 * w0));
    }
}

extern "C" void kernel_launch(void* const* d_in, const int* in_sizes, int n_in,
                              void* d_out, int out_size, void* d_ws, size_t ws_size,
                              hipStream_t stream) {
    const float* feature = (const float*)d_in[0];
    const float* kern    = (const float*)d_in[1];
    float* out           = (float*)d_out;

    dim3 grid(1, HH, NN);   // (1, 160, 8)
    pixelconv_k<<<grid, 320, 0, stream>>>(feature, kern, out);
}

// Round 4
// 45.433 us; speedup vs baseline: 1.1980x; 1.1980x over previous
//
#include <hip/hip_runtime.h>

#define HH 160
#define WW 160
#define CC 32
#define NN 8
#define PIX (HH * WW)   // 25600 = 400 tiles of 64

typedef float f32x2 __attribute__((ext_vector_type(2)));

// Block: 512 threads = 8 channel-groups x 64 flattened pixels.
// Each thread: 4 channels of one pixel. Kernel taps (36 per pixel, shared
// across all 32 channels) staged once per block into LDS, then held in 36
// scalar VGPRs. Grid (400 pixel-tiles, 8 batch).
__global__ __launch_bounds__(512, 6) void pixelconv_k(
    const float* __restrict__ feature,   // [8,32,160,160]
    const float* __restrict__ kern,      // [8,36,160,160]
    float* __restrict__ out)             // [8,32,320,320]
{
    const int tile = blockIdx.x;        // 0..399
    const int n    = blockIdx.y;        // 0..7
    const int t    = threadIdx.x;       // 0..511
    const int lane = t & 63;            // pixel within tile
    const int cg   = t >> 6;            // 0..7 channel group
    const int pixbase = tile * 64;

    // ---- stage kernel[n][0:36][pixbase:pixbase+64] into LDS (9 KB) ----
    __shared__ float kv_lds[36 * 64];
    const float* kbase = kern + (size_t)n * 36 * PIX + pixbase;
    #pragma unroll
    for (int r = 0; r < 4; ++r) {
        const int idx = t + r * 512;    // idx = j*64 + lp
        kv_lds[idx] = kbase[(size_t)(idx >> 6) * PIX + (idx & 63)];
    }
    if (t < 256) {
        const int idx = t + 2048;
        kv_lds[idx] = kbase[(size_t)(idx >> 6) * PIX + (idx & 63)];
    }
    __syncthreads();

    // per-thread copy of the 36 taps for its pixel (conflict-free reads)
    float kv[36];
    #pragma unroll
    for (int j = 0; j < 36; ++j) kv[j] = kv_lds[j * 64 + lane];

    const int pix = pixbase + lane;     // PIX = 400*64 exactly, no guard
    const int h = pix / WW;
    const int w = pix - h * WW;
    const bool hm = (h > 0), hp = (h < HH - 1);
    const bool wm = (w > 0), wp = (w < WW - 1);

    float* outn = out + (size_t)n * CC * 4 * PIX;

    #pragma unroll
    for (int i = 0; i < 4; ++i) {
        const int c = cg * 4 + i;
        const float* fc = feature + ((size_t)(n * CC + c)) * PIX + pix;

        // 9 taps, k = dx*3 + dy -> feature[h+dy-1][w+dx-1]
        float f[9];
        #pragma unroll
        for (int dx = 0; dx < 3; ++dx) {
            #pragma unroll
            for (int dy = 0; dy < 3; ++dy) {
                const bool ok = (dy != 0 || hm) && (dy != 2 || hp) &&
                                (dx != 0 || wm) && (dx != 2 || wp);
                f[dx * 3 + dy] = ok ? fc[(dy - 1) * WW + (dx - 1)] : 0.0f;
            }
        }

        float a0 = 0.f, a1 = 0.f, a2 = 0.f, a3 = 0.f;
        #pragma unroll
        for (int k = 0; k < 9; ++k) {
            a0 = fmaf(f[k], kv[4 * k + 0], a0);
            a1 = fmaf(f[k], kv[4 * k + 1], a1);
            a2 = fmaf(f[k], kv[4 * k + 2], a2);
            a3 = fmaf(f[k], kv[4 * k + 3], a3);
        }

        // pixel shuffle: s = r1*2 + r2 -> out[c][2h+r1][2w+r2]
        float* oc = outn + (size_t)c * 4 * PIX;
        *(f32x2*)(oc + (size_t)(2 * h)     * (2 * WW) + 2 * w) = (f32x2){a0, a1};
        *(f32x2*)(oc + (size_t)(2 * h + 1) * (2 * WW) + 2 * w) = (f32x2){a2, a3};
    }
}

extern "C" void kernel_launch(void* const* d_in, const int* in_sizes, int n_in,
                              void* d_out, int out_size, void* d_ws, size_t ws_size,
                              hipStream_t stream) {
    const float* feature = (const float*)d_in[0];
    const float* kern    = (const float*)d_in[1];
    float* out           = (float*)d_out;

    dim3 grid(PIX / 64, NN, 1);   // (400, 8)
    pixelconv_k<<<grid, 512, 0, stream>>>(feature, kern, out);
}